// Round 11
// baseline (156.208 us; speedup 1.0000x reference)
//
#include <hip/hip_runtime.h>
#include <math.h>

#define N_ROWS 131072
#define DIM 1024
#define KNNK 32
#define NBIN 65536
#define LISTCAP 2048
typedef unsigned int u32;

// ws layout (u32 units):
//   kl    @ 0        (131072 f)
//   hist  @ 131072   (2*65536 u32)
//   state @ 262144   (16 u32) [0..2]=B [3..5]=CB [6]=n_c0 [7]=n_c1 [8]=n_g
//                             [9]=S0(f) [10]=S1(f) [11]=n0_below
//   lv0   @ 262352 lv1 @ 264400 lgv @ 266448 (2048 f each), lgc @ 268496 (2048 u32)

__device__ __forceinline__ float wave_sum(float v) {
#pragma unroll
  for (int off = 32; off > 0; off >>= 1) v += __shfl_xor(v, off, 64);
  return v;
}
__device__ __forceinline__ int wave_sum_i(int v) {
#pragma unroll
  for (int off = 32; off > 0; off >>= 1) v += __shfl_xor(v, off, 64);
  return v;
}
__device__ __forceinline__ u32 wave_sum_u(u32 v) {
#pragma unroll
  for (int off = 32; off > 0; off >>= 1) v += __shfl_xor((int)v, off, 64);
  return v;
}
__device__ __forceinline__ float sum4(float4 a) { return (a.x + a.y) + (a.z + a.w); }
__device__ __forceinline__ float4 sqdiff(float4 a, float m) {
  float4 r;
  r.x = (a.x - m) * (a.x - m);
  r.y = (a.y - m) * (a.y - m);
  r.z = (a.z - m) * (a.z - m);
  r.w = (a.w - m) * (a.w - m);
  return r;
}
__device__ __forceinline__ float acc4(float4 a, float4 m, float mean, float p) {
  float d;
  d = a.x - mean; p += fabsf(d * d - m.x);
  d = a.y - mean; p += fabsf(d * d - m.y);
  d = a.z - mean; p += fabsf(d * d - m.z);
  d = a.w - mean; p += fabsf(d * d - m.w);
  return p;
}

// ---- kernel 1: kl pass (proven R2 body) + hist-zero prologue --------------
// hist is consumed only by kernels after k_kl, so any block may zero any
// slice at start; saves the separate k_zero launch + gap.
__global__ void __launch_bounds__(256) k_kl(const float* __restrict__ A,
                                            const float* __restrict__ q,
                                            float* __restrict__ kl,
                                            u32* __restrict__ hist) {
  int t = threadIdx.x;
  u32 gid = blockIdx.x * 256 + t;
  if (gid < 2 * NBIN) hist[gid] = 0;   // 2048*256 = 524288 >= 131072

  int lane = t & 63;
  int gw = blockIdx.x * 4 + (t >> 6);
  int nw = gridDim.x * 4;

  const float4* Q4 = reinterpret_cast<const float4*>(q);
  float4 q0 = Q4[lane], q1 = Q4[64 + lane], q2 = Q4[128 + lane], q3 = Q4[192 + lane];
  float qs = sum4(q0) + sum4(q1) + sum4(q2) + sum4(q3);
  qs = wave_sum(qs);
  float qm = qs * (1.0f / DIM);
  float4 m0 = sqdiff(q0, qm), m1 = sqdiff(q1, qm),
         m2 = sqdiff(q2, qm), m3 = sqdiff(q3, qm);

  const float4* A4 = reinterpret_cast<const float4*>(A);
  for (int row = gw; row < N_ROWS; row += nw) {
    int rb = row * 256;
    float4 a0 = A4[rb + lane];
    float4 a1 = A4[rb + 64 + lane];
    float4 a2 = A4[rb + 128 + lane];
    float4 a3 = A4[rb + 192 + lane];
    float s = sum4(a0) + sum4(a1) + sum4(a2) + sum4(a3);
    s = wave_sum(s);
    float mean = s * (1.0f / DIM);
    float p = 0.0f;
    p = acc4(a0, m0, mean, p);
    p = acc4(a1, m1, mean, p);
    p = acc4(a2, m2, mean, p);
    p = acc4(a3, m3, mean, p);
    p = wave_sum(p);
    if (lane == 0) kl[row] = p;
  }
}

// ---- kernel 2: histogram, LDS hash-aggregated (unchanged) -----------------
__global__ void __launch_bounds__(256) k_h16(const float* __restrict__ kl,
                                             const int* __restrict__ lab,
                                             u32* __restrict__ hist) {
  __shared__ u32 hkey[2048];
  __shared__ u32 hcnt[2048];
  int t = threadIdx.x;
  for (int j = t; j < 2048; j += 256) { hkey[j] = 0xFFFFFFFFu; hcnt[j] = 0u; }
  __syncthreads();

  int base = blockIdx.x * 1024 + t * 4;  // 128 blocks x 256 thr x 4 elems
  float4 v = *reinterpret_cast<const float4*>(kl + base);
  int4 lb = *reinterpret_cast<const int4*>(lab + base);
  u32 kk[4];
  kk[0] = ((u32)lb.x << 16) | (__float_as_uint(v.x) >> 16);
  kk[1] = ((u32)lb.y << 16) | (__float_as_uint(v.y) >> 16);
  kk[2] = ((u32)lb.z << 16) | (__float_as_uint(v.z) >> 16);
  kk[3] = ((u32)lb.w << 16) | (__float_as_uint(v.w) >> 16);
#pragma unroll
  for (int e = 0; e < 4; ++e) {
    u32 k = kk[e];
    u32 slot = (k * 2654435761u) >> 21;  // 11-bit slot
    for (;;) {
      u32 prev = atomicCAS(&hkey[slot], 0xFFFFFFFFu, k);
      if (prev == 0xFFFFFFFFu || prev == k) { atomicAdd(&hcnt[slot], 1u); break; }
      slot = (slot + 1) & 2047;
    }
  }
  __syncthreads();
  for (int j = t; j < 2048; j += 256) {
    u32 k = hkey[j];
    if (k != 0xFFFFFFFFu) atomicAdd(&hist[k], hcnt[j]);  // k == c*NBIN + key16
  }
}

// ---- kernel 3: single-block scan: chunk sums + find B/CB + zero state -----
// 1024 threads = 16 waves. Phase 1: (selector,chunk) sums via coalesced
// lane-contiguous loads (NOT the R4 per-thread-chunk blunder). Phase 2:
// waves 0..2 scan 64 chunks (shfl), locate boundary bin + count-below.
__global__ void __launch_bounds__(1024) k_scan(const u32* __restrict__ hist,
                                               u32* __restrict__ state) {
  __shared__ u32 csums[3][64];
  __shared__ u32 sB[3], sCB[3];
  int t = threadIdx.x;
  int lane = t & 63, w = t >> 6;  // 16 waves

  for (int job = w; job < 192; job += 16) {
    int s = job >> 6, c = job & 63;
    u32 acc = 0;
#pragma unroll
    for (int i = 0; i < 16; ++i) {
      int bin = c * 1024 + i * 64 + lane;
      acc += (s < 2) ? hist[s * NBIN + bin] : hist[bin] + hist[NBIN + bin];
    }
    acc = wave_sum_u(acc);
    if (lane == 0) csums[s][c] = acc;
  }
  __syncthreads();

  if (w < 3) {
    int s = w;
    u32 own = csums[s][lane];
    u32 incl = own;
#pragma unroll
    for (int off = 1; off < 64; off <<= 1) {
      u32 n = __shfl_up((int)incl, off, 64);
      if (lane >= off) incl += n;
    }
    unsigned long long m = __ballot(incl >= KNNK);
    int C = __ffsll(m) - 1;
    u32 base = __shfl((int)(incl - own), C, 64);
    u32 r = KNNK - base;  // rank within chunk C, in [1, chunkSum]

    u32 h[16], lsum = 0;
#pragma unroll
    for (int i = 0; i < 16; ++i) {
      int bin = C * 1024 + lane * 16 + i;
      h[i] = (s < 2) ? hist[s * NBIN + bin] : hist[bin] + hist[NBIN + bin];
      lsum += h[i];
    }
    u32 pincl = lsum;
#pragma unroll
    for (int off = 1; off < 64; off <<= 1) {
      u32 n = __shfl_up((int)pincl, off, 64);
      if (lane >= off) pincl += n;
    }
    u32 run = pincl - lsum;  // exclusive prefix
#pragma unroll
    for (int i = 0; i < 16; ++i) {
      u32 prev = run;
      run += h[i];
      if (prev < r && run >= r) {
        sB[s] = (u32)(C * 1024 + lane * 16 + i);
        sCB[s] = base + prev;
      }
    }
  }
  __syncthreads();
  if (t < 3) { state[t] = sB[t]; state[3 + t] = sCB[t]; }
  if (t >= 6 && t < 16) state[t] = 0;  // counts/sums for k_collect
}

// ---- kernel 4: collect below-bin sums + boundary-bin lists ----------------
__global__ void __launch_bounds__(256) k_collect(const float* __restrict__ kl,
                                                 const int* __restrict__ lab,
                                                 u32* __restrict__ state,
                                                 float* __restrict__ lv0,
                                                 float* __restrict__ lv1,
                                                 float* __restrict__ lgv,
                                                 u32* __restrict__ lgc) {
  int i = blockIdx.x * 256 + threadIdx.x;
  float v = kl[i];
  int c = lab[i];
  u32 key = __float_as_uint(v) >> 16;
  u32 Bc = state[c];
  u32 Bg = state[2];
  float* S = (float*)&state[9];
  if (key < Bc) {
    atomicAdd(&S[c], v);
  } else if (key == Bc) {
    u32 idx = atomicAdd(&state[6 + c], 1u);
    if (idx < LISTCAP) (c ? lv1 : lv0)[idx] = v;
  }
  if (key < Bg) {
    if (c == 0) atomicAdd(&state[11], 1u);
  } else if (key == Bg) {
    u32 idx = atomicAdd(&state[8], 1u);
    if (idx < LISTCAP) { lgv[idx] = v; lgc[idx] = (u32)c; }
  }
}

// ---- kernel 5: in-bin exact ranking, means, normalize, vote ---------------
__global__ void __launch_bounds__(256) k_finish(const float* __restrict__ lv0g,
                                                const float* __restrict__ lv1g,
                                                const float* __restrict__ lgvg,
                                                const u32* __restrict__ lgcg,
                                                const u32* __restrict__ state,
                                                float* __restrict__ out) {
  __shared__ float lv0[LISTCAP], lv1[LISTCAP], lgv[LISTCAP];
  __shared__ u32 lgc[LISTCAP];
  __shared__ float r_idm[2];
  __shared__ int r_n0;
  int t = threadIdx.x, wid = t >> 6, lane = t & 63;
  int m0 = min((int)state[6], LISTCAP);
  int m1 = min((int)state[7], LISTCAP);
  int mg = min((int)state[8], LISTCAP);
  if (wid == 0) for (int j = lane; j < m0; j += 64) lv0[j] = lv0g[j];
  if (wid == 1) for (int j = lane; j < m1; j += 64) lv1[j] = lv1g[j];
  if (wid == 2) for (int j = lane; j < mg; j += 64) { lgv[j] = lgvg[j]; lgc[j] = lgcg[j]; }
  __syncthreads();

  if (wid < 2) {
    int m = wid ? m1 : m0;
    const float* LV = wid ? lv1 : lv0;
    u32 CB = state[3 + wid];
    float part = 0.0f;
    for (int j = lane; j < m; j += 64) {
      float vj = LV[j];
      int cnt = 0;
      for (int k = 0; k < m; ++k) {
        float vk = LV[k];
        cnt += (vk < vj) || (vk == vj && k < j);
      }
      if (CB + (u32)cnt < KNNK) part += vj;
    }
    part = wave_sum(part);
    if (lane == 0) {
      float S = ((const float*)&state[9])[wid];
      r_idm[wid] = (S + part) * (1.0f / KNNK);
    }
  } else if (wid == 2) {
    u32 CB = state[5];
    int n0p = 0;
    for (int j = lane; j < mg; j += 64) {
      float vj = lgv[j];
      int cnt = 0;
      for (int k = 0; k < mg; ++k) {
        float vk = lgv[k];
        cnt += (vk < vj) || (vk == vj && k < j);
      }
      if (CB + (u32)cnt < KNNK && lgc[j] == 0u) n0p++;
    }
    n0p = wave_sum_i(n0p);
    if (lane == 0) r_n0 = (int)state[11] + n0p;
  }
  __syncthreads();
  if (t == 0) {
    float id0 = r_idm[0], id1 = r_idm[1];
    float den = fmaxf(fabsf(id0) + fabsf(id1), 1e-12f);
    out[0] = (r_n0 >= KNNK / 2) ? 0.0f : 1.0f;  // argmax, first-wins on tie
    out[1] = id0 / den;
    out[2] = id1 / den;
  }
}

extern "C" void kernel_launch(void* const* d_in, const int* in_sizes, int n_in,
                              void* d_out, int out_size, void* d_ws, size_t ws_size,
                              hipStream_t stream) {
  const float* query = (const float*)d_in[0];
  const float* anchor = (const float*)d_in[1];
  const int* label = (const int*)d_in[2];
  float* out = (float*)d_out;

  u32* w = (u32*)d_ws;
  float* kl = (float*)w;            // 131072
  u32* hist = w + 131072;           // 131072
  u32* state = w + 262144;          // 16
  float* lv0 = (float*)(w + 262352);
  float* lv1 = (float*)(w + 264400);
  float* lgv = (float*)(w + 266448);
  u32* lgc = w + 268496;

  k_kl<<<2048, 256, 0, stream>>>(anchor, query, kl, hist);
  k_h16<<<128, 256, 0, stream>>>(kl, label, hist);
  k_scan<<<1, 1024, 0, stream>>>(hist, state);
  k_collect<<<512, 256, 0, stream>>>(kl, label, state, lv0, lv1, lgv, lgc);
  k_finish<<<1, 256, 0, stream>>>(lv0, lv1, lgv, lgc, state, out);
}

// Round 12
// 124.573 us; speedup vs baseline: 1.2539x; 1.2539x over previous
//
#include <hip/hip_runtime.h>
#include <math.h>

#define N_ROWS 131072
#define DIM 1024
#define KNNK 32
#define NBIN 65536
#define LISTCAP 2048
typedef unsigned int u32;
typedef float f32x4 __attribute__((ext_vector_type(4)));

// ws layout (u32 units):
//   kl    @ 0        (131072 f)
//   hist  @ 131072   (2*65536 u32)
//   state @ 262144   (16 u32) [0..2]=B [3..5]=CB [6]=n_c0 [7]=n_c1 [8]=n_g
//                             [9]=S0(f) [10]=S1(f) [11]=n0_below
//   csum  @ 262160   (192 u32)
//   lv0   @ 262352 lv1 @ 264400 lgv @ 266448 (2048 f each), lgc @ 268496 (2048 u32)

__device__ __forceinline__ float wave_sum(float v) {
#pragma unroll
  for (int off = 32; off > 0; off >>= 1) v += __shfl_xor(v, off, 64);
  return v;
}
__device__ __forceinline__ int wave_sum_i(int v) {
#pragma unroll
  for (int off = 32; off > 0; off >>= 1) v += __shfl_xor(v, off, 64);
  return v;
}
__device__ __forceinline__ float sum4v(f32x4 a) { return (a.x + a.y) + (a.z + a.w); }
__device__ __forceinline__ f32x4 sqdiffv(f32x4 a, float m) {
  f32x4 r;
  r.x = (a.x - m) * (a.x - m);
  r.y = (a.y - m) * (a.y - m);
  r.z = (a.z - m) * (a.z - m);
  r.w = (a.w - m) * (a.w - m);
  return r;
}
__device__ __forceinline__ float acc4v(f32x4 a, f32x4 m, float mean, float p) {
  float d;
  d = a.x - mean; p += fabsf(d * d - m.x);
  d = a.y - mean; p += fabsf(d * d - m.y);
  d = a.z - mean; p += fabsf(d * d - m.z);
  d = a.w - mean; p += fabsf(d * d - m.w);
  return p;
}

// ---- kernel 1: kl pass (proven body) + hist-zero prologue + NT loads ------
// NEW this round: anchor loads are non-temporal (touch-once 512MB stream,
// skip L2/LLC fill). Everything else is the measured-117us R2 body.
__global__ void __launch_bounds__(256) k_kl(const float* __restrict__ A,
                                            const float* __restrict__ q,
                                            float* __restrict__ kl,
                                            u32* __restrict__ hist) {
  int t = threadIdx.x;
  u32 gid = blockIdx.x * 256 + t;
  if (gid < 2 * NBIN) hist[gid] = 0;

  int lane = t & 63;
  int gw = blockIdx.x * 4 + (t >> 6);
  int nw = gridDim.x * 4;

  const f32x4* Q4 = reinterpret_cast<const f32x4*>(q);
  f32x4 q0 = Q4[lane], q1 = Q4[64 + lane], q2 = Q4[128 + lane], q3 = Q4[192 + lane];
  float qs = sum4v(q0) + sum4v(q1) + sum4v(q2) + sum4v(q3);
  qs = wave_sum(qs);
  float qm = qs * (1.0f / DIM);
  f32x4 m0 = sqdiffv(q0, qm), m1 = sqdiffv(q1, qm),
        m2 = sqdiffv(q2, qm), m3 = sqdiffv(q3, qm);

  const f32x4* A4 = reinterpret_cast<const f32x4*>(A);
  for (int row = gw; row < N_ROWS; row += nw) {
    int rb = row * 256;
    f32x4 a0 = __builtin_nontemporal_load(A4 + rb + lane);
    f32x4 a1 = __builtin_nontemporal_load(A4 + rb + 64 + lane);
    f32x4 a2 = __builtin_nontemporal_load(A4 + rb + 128 + lane);
    f32x4 a3 = __builtin_nontemporal_load(A4 + rb + 192 + lane);
    float s = sum4v(a0) + sum4v(a1) + sum4v(a2) + sum4v(a3);
    s = wave_sum(s);
    float mean = s * (1.0f / DIM);
    float p = 0.0f;
    p = acc4v(a0, m0, mean, p);
    p = acc4v(a1, m1, mean, p);
    p = acc4v(a2, m2, mean, p);
    p = acc4v(a3, m3, mean, p);
    p = wave_sum(p);
    if (lane == 0) kl[row] = p;
  }
}

// ---- kernel 2: histogram, LDS hash-aggregated (unchanged) -----------------
__global__ void __launch_bounds__(256) k_h16(const float* __restrict__ kl,
                                             const int* __restrict__ lab,
                                             u32* __restrict__ hist) {
  __shared__ u32 hkey[2048];
  __shared__ u32 hcnt[2048];
  int t = threadIdx.x;
  for (int j = t; j < 2048; j += 256) { hkey[j] = 0xFFFFFFFFu; hcnt[j] = 0u; }
  __syncthreads();

  int base = blockIdx.x * 1024 + t * 4;  // 128 blocks x 256 thr x 4 elems
  float4 v = *reinterpret_cast<const float4*>(kl + base);
  int4 lb = *reinterpret_cast<const int4*>(lab + base);
  u32 kk[4];
  kk[0] = ((u32)lb.x << 16) | (__float_as_uint(v.x) >> 16);
  kk[1] = ((u32)lb.y << 16) | (__float_as_uint(v.y) >> 16);
  kk[2] = ((u32)lb.z << 16) | (__float_as_uint(v.z) >> 16);
  kk[3] = ((u32)lb.w << 16) | (__float_as_uint(v.w) >> 16);
#pragma unroll
  for (int e = 0; e < 4; ++e) {
    u32 k = kk[e];
    u32 slot = (k * 2654435761u) >> 21;  // 11-bit slot
    for (;;) {
      u32 prev = atomicCAS(&hkey[slot], 0xFFFFFFFFu, k);
      if (prev == 0xFFFFFFFFu || prev == k) { atomicAdd(&hcnt[slot], 1u); break; }
      slot = (slot + 1) & 2047;
    }
  }
  __syncthreads();
  for (int j = t; j < 2048; j += 256) {
    u32 k = hkey[j];
    if (k != 0xFFFFFFFFu) atomicAdd(&hist[k], hcnt[j]);  // k == c*NBIN + key16
  }
}

// ---- kernel 3: per-(selector,chunk) sums, 192 parallel blocks -------------
__global__ void __launch_bounds__(256) k_scan1(const u32* __restrict__ hist,
                                               u32* __restrict__ csum) {
  __shared__ u32 sc[256];
  int b = blockIdx.x, t = threadIdx.x;
  int s = b >> 6, c = b & 63;
  int base = c * 1024;
  u32 v = 0;
#pragma unroll
  for (int j = 0; j < 4; ++j) {
    int i = base + t + 256 * j;
    v += (s < 2) ? hist[s * NBIN + i] : hist[i] + hist[NBIN + i];
  }
  sc[t] = v;
  __syncthreads();
  for (int off = 128; off > 0; off >>= 1) {
    if (t < off) sc[t] += sc[t + off];
    __syncthreads();
  }
  if (t == 0) csum[b] = sc[0];
}

// ---- kernel 4: find bin B + count-below CB per selector; zero state -------
__global__ void __launch_bounds__(256) k_scan2(const u32* __restrict__ hist,
                                               const u32* __restrict__ csum,
                                               u32* __restrict__ state) {
  __shared__ u32 sc[256];
  __shared__ int sC;
  __shared__ u32 sBase;
  int t = threadIdx.x;
  if (t >= 6 && t < 16) state[t] = 0;  // counters/sums for k_collect
  for (int s = 0; s < 3; ++s) {
    if (t < 64) {
      u32 own = csum[s * 64 + t];
      u32 incl = own;
#pragma unroll
      for (int off = 1; off < 64; off <<= 1) {
        u32 n = __shfl_up(incl, off, 64);
        if (t >= off) incl += n;
      }
      unsigned long long m = __ballot(incl >= KNNK);
      int C = __ffsll(m) - 1;
      u32 base = __shfl(incl - own, C, 64);
      if (t == 0) { sC = C; sBase = base; }
    }
    __syncthreads();
    int C = sC;
    u32 base = sBase;
    u32 r = KNNK - base;  // rank within chunk, in [1,32]
    int gb = C * 1024 + 4 * t;
    u32 h[4], loc = 0;
#pragma unroll
    for (int j = 0; j < 4; ++j) {
      int i = gb + j;
      h[j] = (s < 2) ? hist[s * NBIN + i] : hist[i] + hist[NBIN + i];
      loc += h[j];
    }
    sc[t] = loc;
    __syncthreads();
    for (int off = 1; off < 256; off <<= 1) {
      u32 v2 = (t >= off) ? sc[t - off] : 0;
      __syncthreads();
      sc[t] += v2;
      __syncthreads();
    }
    u32 run = sc[t] - loc;  // exclusive within chunk
#pragma unroll
    for (int j = 0; j < 4; ++j) {
      u32 prev = run;
      run += h[j];
      if (run >= r && prev < r) {
        state[s] = (u32)(gb + j);
        state[3 + s] = base + prev;
      }
    }
    __syncthreads();
  }
}

// ---- kernel 5: collect below-bin sums + boundary-bin lists ----------------
__global__ void __launch_bounds__(256) k_collect(const float* __restrict__ kl,
                                                 const int* __restrict__ lab,
                                                 u32* __restrict__ state,
                                                 float* __restrict__ lv0,
                                                 float* __restrict__ lv1,
                                                 float* __restrict__ lgv,
                                                 u32* __restrict__ lgc) {
  int i = blockIdx.x * 256 + threadIdx.x;
  float v = kl[i];
  int c = lab[i];
  u32 key = __float_as_uint(v) >> 16;
  u32 Bc = state[c];
  u32 Bg = state[2];
  float* S = (float*)&state[9];
  if (key < Bc) {
    atomicAdd(&S[c], v);
  } else if (key == Bc) {
    u32 idx = atomicAdd(&state[6 + c], 1u);
    if (idx < LISTCAP) (c ? lv1 : lv0)[idx] = v;
  }
  if (key < Bg) {
    if (c == 0) atomicAdd(&state[11], 1u);
  } else if (key == Bg) {
    u32 idx = atomicAdd(&state[8], 1u);
    if (idx < LISTCAP) { lgv[idx] = v; lgc[idx] = (u32)c; }
  }
}

// ---- kernel 6: in-bin exact ranking, means, normalize, vote ---------------
__global__ void __launch_bounds__(256) k_finish(const float* __restrict__ lv0g,
                                                const float* __restrict__ lv1g,
                                                const float* __restrict__ lgvg,
                                                const u32* __restrict__ lgcg,
                                                const u32* __restrict__ state,
                                                float* __restrict__ out) {
  __shared__ float lv0[LISTCAP], lv1[LISTCAP], lgv[LISTCAP];
  __shared__ u32 lgc[LISTCAP];
  __shared__ float r_idm[2];
  __shared__ int r_n0;
  int t = threadIdx.x, wid = t >> 6, lane = t & 63;
  int m0 = min((int)state[6], LISTCAP);
  int m1 = min((int)state[7], LISTCAP);
  int mg = min((int)state[8], LISTCAP);
  if (wid == 0) for (int j = lane; j < m0; j += 64) lv0[j] = lv0g[j];
  if (wid == 1) for (int j = lane; j < m1; j += 64) lv1[j] = lv1g[j];
  if (wid == 2) for (int j = lane; j < mg; j += 64) { lgv[j] = lgvg[j]; lgc[j] = lgcg[j]; }
  __syncthreads();

  if (wid < 2) {
    int m = wid ? m1 : m0;
    const float* LV = wid ? lv1 : lv0;
    u32 CB = state[3 + wid];
    float part = 0.0f;
    for (int j = lane; j < m; j += 64) {
      float vj = LV[j];
      int cnt = 0;
      for (int k = 0; k < m; ++k) {
        float vk = LV[k];
        cnt += (vk < vj) || (vk == vj && k < j);
      }
      if (CB + (u32)cnt < KNNK) part += vj;
    }
    part = wave_sum(part);
    if (lane == 0) {
      float S = ((const float*)&state[9])[wid];
      r_idm[wid] = (S + part) * (1.0f / KNNK);
    }
  } else if (wid == 2) {
    u32 CB = state[5];
    int n0p = 0;
    for (int j = lane; j < mg; j += 64) {
      float vj = lgv[j];
      int cnt = 0;
      for (int k = 0; k < mg; ++k) {
        float vk = lgv[k];
        cnt += (vk < vj) || (vk == vj && k < j);
      }
      if (CB + (u32)cnt < KNNK && lgc[j] == 0u) n0p++;
    }
    n0p = wave_sum_i(n0p);
    if (lane == 0) r_n0 = (int)state[11] + n0p;
  }
  __syncthreads();
  if (t == 0) {
    float id0 = r_idm[0], id1 = r_idm[1];
    float den = fmaxf(fabsf(id0) + fabsf(id1), 1e-12f);
    out[0] = (r_n0 >= KNNK / 2) ? 0.0f : 1.0f;  // argmax, first-wins on tie
    out[1] = id0 / den;
    out[2] = id1 / den;
  }
}

extern "C" void kernel_launch(void* const* d_in, const int* in_sizes, int n_in,
                              void* d_out, int out_size, void* d_ws, size_t ws_size,
                              hipStream_t stream) {
  const float* query = (const float*)d_in[0];
  const float* anchor = (const float*)d_in[1];
  const int* label = (const int*)d_in[2];
  float* out = (float*)d_out;

  u32* w = (u32*)d_ws;
  float* kl = (float*)w;            // 131072
  u32* hist = w + 131072;           // 131072
  u32* state = w + 262144;          // 16
  u32* csum = w + 262160;           // 192
  float* lv0 = (float*)(w + 262352);
  float* lv1 = (float*)(w + 264400);
  float* lgv = (float*)(w + 266448);
  u32* lgc = w + 268496;

  k_kl<<<2048, 256, 0, stream>>>(anchor, query, kl, hist);
  k_h16<<<128, 256, 0, stream>>>(kl, label, hist);
  k_scan1<<<192, 256, 0, stream>>>(hist, csum);
  k_scan2<<<1, 256, 0, stream>>>(hist, csum, state);
  k_collect<<<512, 256, 0, stream>>>(kl, label, state, lv0, lv1, lgv, lgc);
  k_finish<<<1, 256, 0, stream>>>(lv0, lv1, lgv, lgc, state, out);
}